// Round 11
// baseline (1908.602 us; speedup 1.0000x reference)
//
#include <hip/hip_runtime.h>
#include <hip/hip_bf16.h>
#include <cstdint>
#include <cstddef>

constexpr int NTRAIN = 4096;
constexpr int NEDGES = 131072;
constexpr int DSRC = 2500, DH = 2500, DNC = 16;
constexpr int KD1 = 2659;   // trainf cols
constexpr int KC3 = 5175;   // conv3 cat K real (2675 + 2500)
constexpr int KP3 = 5184;   // conv3 cat K padded (81*64)
constexpr int KC4 = 5000;   // conv4 cat K real
constexpr int KP4 = 5056;   // conv4 cat K padded (79*64)
constexpr int KPH = 2560;   // 2500 padded to mult of 64 (40*64)
constexpr int NPW = 2560;   // 2500 padded to mult of 256
constexpr int NQKV = 7680;  // 3*2560 fused qkv width
constexpr int GSTR = 2504;  // bf16 gene row stride (313*8)
constexpr float EPSV = 1e-5f;
constexpr float SLOPEV = 0.01f;

typedef __attribute__((ext_vector_type(8))) short bf16x8;
typedef __attribute__((ext_vector_type(4))) float f32x4;

static __device__ __forceinline__ unsigned short bfbits(float f) {
    __hip_bfloat16 h = __float2bfloat16(f);
    return *reinterpret_cast<unsigned short*>(&h);
}
static __device__ __forceinline__ float b2f(short s) {
    return __uint_as_float(((unsigned)(unsigned short)s) << 16);
}

// ---------------- CSR build ----------------
__global__ void count_deg_k(const int* __restrict__ edst, int* __restrict__ deg) {
    int e = blockIdx.x * 256 + threadIdx.x;
    if (e < NEDGES) atomicAdd(&deg[edst[e]], 1);
}

__global__ __launch_bounds__(1024) void scan_deg_k(const int* __restrict__ deg,
                                                   int* __restrict__ indptr,
                                                   int* __restrict__ cursor) {
    __shared__ int sums[1024];
    int t = threadIdx.x;
    int base = t * 4;
    int d0 = deg[base + 0], d1 = deg[base + 1], d2 = deg[base + 2], d3 = deg[base + 3];
    sums[t] = d0 + d1 + d2 + d3;
    __syncthreads();
    for (int o = 1; o < 1024; o <<= 1) {
        int v = (t >= o) ? sums[t - o] : 0;
        __syncthreads();
        sums[t] += v;
        __syncthreads();
    }
    int excl = (t == 0) ? 0 : sums[t - 1];
    int p0 = excl, p1 = p0 + d0, p2 = p1 + d1, p3 = p2 + d2;
    indptr[base + 0] = p0; indptr[base + 1] = p1; indptr[base + 2] = p2; indptr[base + 3] = p3;
    cursor[base + 0] = p0; cursor[base + 1] = p1; cursor[base + 2] = p2; cursor[base + 3] = p3;
    if (t == 1023) indptr[4096] = p3 + d3;
}

__global__ void scatter_edges_k(const int* __restrict__ esrc, const int* __restrict__ edst,
                                int* __restrict__ cursor, int* __restrict__ csr_src) {
    int e = blockIdx.x * 256 + threadIdx.x;
    if (e < NEDGES) {
        int d = edst[e];
        int p = atomicAdd(&cursor[d], 1);
        csr_src[p] = esrc[e];
    }
}

// fp32 gene [20000][2500] -> bf16 [20000][GSTR] (cols 2500..2503 zeroed)
__global__ __launch_bounds__(256) void gene2bf_k(const float* __restrict__ gene,
                                                 short* __restrict__ gbf) {
    int v = blockIdx.x * 256 + threadIdx.x;
    if (v >= 313) return;
    int row = blockIdx.y;
    const float* src = gene + (size_t)row * DSRC + v * 8;
    f32x4 a = *(const f32x4*)(src);
    f32x4 b = {0.f, 0.f, 0.f, 0.f};
    if (v < 312) b = *(const f32x4*)(src + 4);
    bf16x8 o;
#pragma unroll
    for (int c = 0; c < 4; c++) o[c] = (short)bfbits(a[c]);
#pragma unroll
    for (int c = 0; c < 4; c++) o[4 + c] = (short)bfbits(b[c]);
    *(bf16x8*)(gbf + (size_t)row * GSTR + v * 8) = o;
}

// neighbor mean over bf16 gene table; writes bf16 into BOTH concat-A buffers.
__global__ __launch_bounds__(256) void sage_mean_k(const short* __restrict__ gbf,
                                                   const int* __restrict__ indptr,
                                                   const int* __restrict__ csr_src,
                                                   __hip_bfloat16* __restrict__ A3,
                                                   __hip_bfloat16* __restrict__ A4) {
    int row = blockIdx.x;
    int s = indptr[row], e = indptr[row + 1];
    int t = threadIdx.x;
    float a0[8], a1[8];
#pragma unroll
    for (int c = 0; c < 8; c++) { a0[c] = 0.f; a1[c] = 0.f; }
    bool has1 = (t < 57);  // t+256 < 313
    int j = s;
    for (; j + 2 <= e; j += 2) {
        const bf16x8* g0 = (const bf16x8*)(gbf + (size_t)csr_src[j] * GSTR);
        const bf16x8* g1 = (const bf16x8*)(gbf + (size_t)csr_src[j + 1] * GSTR);
        bf16x8 u0 = g0[t], w0 = g1[t];
        bf16x8 u1, w1;
        if (has1) { u1 = g0[t + 256]; w1 = g1[t + 256]; }
#pragma unroll
        for (int c = 0; c < 8; c++) a0[c] += b2f(u0[c]) + b2f(w0[c]);
        if (has1) {
#pragma unroll
            for (int c = 0; c < 8; c++) a1[c] += b2f(u1[c]) + b2f(w1[c]);
        }
    }
    if (j < e) {
        const bf16x8* g0 = (const bf16x8*)(gbf + (size_t)csr_src[j] * GSTR);
        bf16x8 u0 = g0[t];
#pragma unroll
        for (int c = 0; c < 8; c++) a0[c] += b2f(u0[c]);
        if (has1) {
            bf16x8 u1 = g0[t + 256];
#pragma unroll
            for (int c = 0; c < 8; c++) a1[c] += b2f(u1[c]);
        }
    }
    float inv = 1.f / fmaxf((float)(e - s), 1.f);
#pragma unroll
    for (int c = 0; c < 8; c++) {
        int f = t * 8 + c;  // < 2048
        __hip_bfloat16 h = __float2bfloat16(a0[c] * inv);
        A3[(size_t)row * KP3 + 2675 + f] = h;
        A4[(size_t)row * KP4 + 2500 + f] = h;
    }
    if (has1) {
#pragma unroll
        for (int c = 0; c < 8; c++) {
            int f = (t + 256) * 8 + c;
            if (f < 2500) {
                __hip_bfloat16 h = __float2bfloat16(a1[c] * inv);
                A3[(size_t)row * KP3 + 2675 + f] = h;
                A4[(size_t)row * KP4 + 2500 + f] = h;
            }
        }
    }
}

// build [trainf | yhat] part of conv3 concat A (cols [0,2675) and pad [5175,5184))
__global__ void dst_build_k(const float* __restrict__ trainf, const float* __restrict__ yhat,
                            __hip_bfloat16* __restrict__ A3) {
    int c = blockIdx.x * 256 + threadIdx.x;
    int r = blockIdx.y;
    if (c >= KP3) return;
    if (c >= 2675 && c < KC3) return;  // sage_mean's region
    float v = 0.f;
    if (c < KD1) v = trainf[(size_t)r * KD1 + c];
    else if (c < 2675) v = yhat[r * DNC + (c - KD1)];
    A3[(size_t)r * KP3 + c] = __float2bfloat16(v);
}

// transpose (optionally 2-source concat along k) fp32 [K][Nreal] -> bf16 [Npad][Kpad]
__global__ __launch_bounds__(256) void wtrans_k(const float* __restrict__ W1,
                                                const float* __restrict__ W2, int ldw,
                                                __hip_bfloat16* __restrict__ Wt,
                                                int Nreal, int K1, int K12, int Kpad, int Npad) {
    __shared__ float tile[32][33];
    int k0 = blockIdx.x * 32, n0 = blockIdx.y * 32;
    int x = threadIdx.x & 31, y = threadIdx.x >> 5;
#pragma unroll
    for (int i = 0; i < 32; i += 8) {
        int k = k0 + y + i, n = n0 + x;
        float v = 0.f;
        if (n < Nreal) {
            if (k < K1) v = W1[(size_t)k * ldw + n];
            else if (k < K12) v = W2[(size_t)(k - K1) * ldw + n];
        }
        tile[y + i][x] = v;
    }
    __syncthreads();
#pragma unroll
    for (int i = 0; i < 32; i += 8) {
        int n = n0 + y + i, k = k0 + x;
        if (n < Npad && k < Kpad) Wt[(size_t)n * Kpad + k] = __float2bfloat16(tile[x][y + i]);
    }
}

// bf16 [4096][cols @ ldv] -> bf16 [2560][4096] transpose (v -> vT)
__global__ __launch_bounds__(256) void btrans_k(const __hip_bfloat16* __restrict__ V, int ldv,
                                                __hip_bfloat16* __restrict__ VT) {
    __shared__ __hip_bfloat16 tile[32][33];
    int r0 = blockIdx.x * 32, c0 = blockIdx.y * 32;
    int x = threadIdx.x & 31, y = threadIdx.x >> 5;
#pragma unroll
    for (int i = 0; i < 32; i += 8)
        tile[y + i][x] = V[(size_t)(r0 + y + i) * ldv + c0 + x];
    __syncthreads();
#pragma unroll
    for (int i = 0; i < 32; i += 8)
        VT[(size_t)(c0 + y + i) * NTRAIN + r0 + x] = tile[x][y + i];
}

// concat bias [bq|bk|bv] -> [7680] with zero pads
__global__ void qkv_bias_k(const float* __restrict__ bq, const float* __restrict__ bk,
                           const float* __restrict__ bv, float* __restrict__ bqkv) {
    int i = blockIdx.x * 256 + threadIdx.x;
    if (i >= NQKV) return;
    int j = i / KPH, c = i % KPH;
    const float* src = (j == 0) ? bq : (j == 1) ? bk : bv;
    bqkv[i] = (c < DH) ? src[c] : 0.f;
}

// ---------------- 256x256 8-phase MFMA bf16 GEMM (R3/R8 exact — best measured) ----------------
// C[M,N] = alpha*A[M,K]@Bt[N,K]^T (+bias)(+relu); out fp32 (Cf) or bf16 (Cb, cols with
// (n % nmod) >= N zero-filled). BK=64, 8 waves (2Mx4N), double-buffered 128KB LDS,
// st_16x32 swizzle. Per K-tile: 4 phases, counted vmcnt(4) at phases 1/3.
// Fused BN column-partials (psOut!=null, fp32-out path): ps[by][n], grid.y=16 partition.
// FAT LAUNCH: blocks with orig >= ngemm are aux weight-transpose workers (up to 3 slabs,
// wtrans-identical math, 512-thr tiles) — fills the 96 idle CUs of 160-block dispatches.
// Swizzle is over ngemm only; aux blocks have higher by -> dispatched after GEMM blocks.
// EXPLORED-AND-REJECTED (measured, do not retry):
//  - runtime-slot 4-ring (R4-R6): regalloc cliff, 5.5 GB scratch, 8x slower.
//  - merged 32-MFMA phases (R7): 38->33% MfmaUtil.
//  - static 4-slot deep pipeline, vmcnt(8) (R9): clean codegen but 181->195us — stall is
//    the barrier-lockstep LDS<->MFMA alternation; R3's exact 4-phase shape is optimal.
__device__ __forceinline__ void async_cp16(const void* g, void* l) {
    __builtin_amdgcn_global_load_lds((const __attribute__((address_space(1))) void*)g,
                                     (__attribute__((address_space(3))) void*)l, 16, 0, 0);
}
#define WAITVM(N) asm volatile("s_waitcnt vmcnt(" #N ")" ::: "memory")
#define LGKM0 asm volatile("s_waitcnt lgkmcnt(0)" ::: "memory")
#define SB __builtin_amdgcn_sched_barrier(0)
static __device__ __forceinline__ void bar_raw() {
    asm volatile("" ::: "memory");
    __builtin_amdgcn_s_barrier();
    asm volatile("" ::: "memory");
}

__global__ __launch_bounds__(512, 2) void gemm256_k(const short* __restrict__ A,
                                                    const short* __restrict__ Bt,
                                                    const float* __restrict__ bias,
                                                    float* __restrict__ Cf,
                                                    __hip_bfloat16* __restrict__ Cb,
                                                    float* __restrict__ psOut,
                                                    float* __restrict__ ps2Out,
                                                    int N, int K, int sA, int sB, int ldc,
                                                    int nmod, float alpha, int act,
                                                    int ngemm,
                                                    const float* xs0, const float* xs1,
                                                    const float* xs2, const float* xs3,
                                                    const float* xs4, const float* xs5,
                                                    short* xout, long xstride,
                                                    int xldw, int xNreal, int xK1, int xK12,
                                                    int xKpad, int xNpad, int nslab) {
    __shared__ short smem[65536];  // GEMM: [buf][A|B]; aux: fp32 tile scratch
    int nwgt = gridDim.x * gridDim.y;
    int orig = blockIdx.y * gridDim.x + blockIdx.x;

    if (orig >= ngemm) {
        // ---- aux weight-transpose worker ----
        int wid = orig - ngemm, nw = nwgt - ngemm;
        float* tile = (float*)smem;  // [32][33]
        int tid = threadIdx.x;
        int x = tid & 31, y0 = tid >> 5;  // y0: 0..15
        int ntx = xKpad >> 5, nty = xNpad >> 5;
        int per = ntx * nty, total = nslab * per;
        for (int t = wid; t < total; t += nw) {
            int sl = t / per, rem = t - sl * per;
            int tx = rem % ntx, ty = rem / ntx;
            const float* W1 = (sl == 0) ? xs0 : (sl == 1) ? xs2 : xs4;
            const float* W2 = (sl == 0) ? xs1 : (sl == 1) ? xs3 : xs5;
            short* out = xout + (size_t)sl * xstride;
            int k0 = tx * 32, n0 = ty * 32;
            __syncthreads();  // tile reuse guard
#pragma unroll
            for (int i = 0; i < 32; i += 16) {
                int k = k0 + y0 + i, n = n0 + x;
                float v = 0.f;
                if (n < xNreal) {
                    if (k < xK1) v = W1[(size_t)k * xldw + n];
                    else if (k < xK12) v = W2[(size_t)(k - xK1) * xldw + n];
                }
                tile[(y0 + i) * 33 + x] = v;
            }
            __syncthreads();
#pragma unroll
            for (int i = 0; i < 32; i += 16) {
                int n = n0 + y0 + i, k = k0 + x;
                out[(size_t)n * xKpad + k] = (short)bfbits(tile[x * 33 + y0 + i]);
            }
        }
        return;
    }

    // bijective XCD swizzle over the GEMM blocks only
    int nwg = ngemm;
    int qd = nwg >> 3, rr = nwg & 7;
    int xcd = orig & 7, oidx = orig >> 3;
    int nb = (xcd < rr ? xcd * (qd + 1) : rr * (qd + 1) + (xcd - rr) * qd) + oidx;
    int bx = nb % gridDim.x, by = nb / gridDim.x;
    int row0 = by * 256, col0 = bx * 256;

    int tid = threadIdx.x;
    int wave = tid >> 6, lane = tid & 63;
    int wm = wave >> 2, wn = wave & 3;

    // staging: per-lane inverse-swizzled source; LDS dest = subtile base + lane*16
    int rsub = lane >> 2;
    int cs = ((lane & 3) * 8) ^ ((lane >= 32) ? 16 : 0);
    const short* gA0 = A + (size_t)(row0 + wave * 16 + rsub) * sA + cs;
    const short* gA1 = A + (size_t)(row0 + wave * 16 + 128 + rsub) * sA + cs;
    const short* gB0 = Bt + (size_t)(col0 + wave * 16 + rsub) * sB + cs;
    const short* gB1 = Bt + (size_t)(col0 + wave * 16 + 128 + rsub) * sB + cs;
    int sa0 = wave * 1024;         // subtile (rb=wave, kb=0) base, shorts
    int sa1 = (wave + 8) * 1024;   // subtile (rb=wave+8, kb=0)

    // swizzled ds_read offset within subtile (shorts)
    int fr = lane & 15, kq = lane >> 4;
    int roff = fr * 32 + ((kq * 8) ^ ((fr & 8) ? 16 : 0));

    f32x4 acc[8][4];
#pragma unroll
    for (int i = 0; i < 8; i++)
#pragma unroll
        for (int j = 0; j < 4; j++)
#pragma unroll
            for (int r = 0; r < 4; r++) acc[i][j][r] = 0.f;

#define STAGE_A(kb, b, k0s) { \
    short* l0 = smem + (b) * 32768 + sa0 + (kb) * 512; \
    short* l1 = smem + (b) * 32768 + sa1 + (kb) * 512; \
    async_cp16(gA0 + (k0s) + (kb) * 32, l0); \
    async_cp16(gA1 + (k0s) + (kb) * 32, l1); }
#define STAGE_B(kb, b, k0s) { \
    short* l0 = smem + (b) * 32768 + 16384 + sa0 + (kb) * 512; \
    short* l1 = smem + (b) * 32768 + 16384 + sa1 + (kb) * 512; \
    async_cp16(gB0 + (k0s) + (kb) * 32, l0); \
    async_cp16(gB1 + (k0s) + (kb) * 32, l1); }
#define DSRA(dst, mq, kk) \
    _Pragma("unroll") for (int i = 0; i < 4; i++) \
        dst[i] = *(const bf16x8*)(ab + (((wm * 8 + (mq) * 4 + i) * 2 + (kk)) << 9) + roff);
#define DSRB(dst, kk) \
    _Pragma("unroll") for (int j = 0; j < 4; j++) \
        dst[j] = *(const bf16x8*)(bb + (((wn * 4 + j) * 2 + (kk)) << 9) + roff);
#define MFMA16(av, bvv, mq) \
    __builtin_amdgcn_s_setprio(1); \
    _Pragma("unroll") for (int i = 0; i < 4; i++) \
        _Pragma("unroll") for (int j = 0; j < 4; j++) \
            acc[(mq) * 4 + i][j] = __builtin_amdgcn_mfma_f32_16x16x32_bf16(av[i], bvv[j], acc[(mq) * 4 + i][j], 0, 0, 0); \
    __builtin_amdgcn_s_setprio(0);

    int nt = K >> 6;
    // prologue: tile 0's 4 half-groups into buf0 (order AK0,BK0,AK1,BK1)
    STAGE_A(0, 0, 0); STAGE_B(0, 0, 0); STAGE_A(1, 0, 0); STAGE_B(1, 0, 0);
    WAITVM(4);   // AK0,BK0 landed; AK1,BK1 in flight
    bar_raw();
    int buf = 0;
    for (int t = 0; t < nt - 1; ++t) {
        const short* ab = smem + (buf << 15);
        const short* bb = ab + 16384;
        int k1 = (t + 1) << 6;
        bf16x8 a0[4], a1[4], b0[4], b1[4];
        // p0: reads K-half0; stages next tile's AK0
        DSRA(a0, 0, 0); DSRB(b0, 0);
        STAGE_A(0, buf ^ 1, k1);
        bar_raw(); LGKM0; SB;
        MFMA16(a0, b0, 0);
        SB; bar_raw();
        // p1: stages BK0; vmcnt drains this tile's AK1,BK1 (needed at p2)
        DSRA(a1, 1, 0);
        STAGE_B(0, buf ^ 1, k1);
        WAITVM(4);
        bar_raw(); LGKM0; SB;
        MFMA16(a1, b0, 1);
        SB; bar_raw();
        // p2: reads K-half1; stages AK1
        DSRA(a0, 0, 1); DSRB(b1, 1);
        STAGE_A(1, buf ^ 1, k1);
        bar_raw(); LGKM0; SB;
        MFMA16(a0, b1, 0);
        SB; bar_raw();
        // p3: stages BK1; vmcnt drains next tile's AK0,BK0 (needed at next p0)
        DSRA(a1, 1, 1);
        STAGE_B(1, buf ^ 1, k1);
        WAITVM(4);
        bar_raw(); LGKM0; SB;
        MFMA16(a1, b1, 1);
        SB; bar_raw();
        buf ^= 1;
    }
    {   // final tile: no staging; drain remaining loads before K-half1 reads
        const short* ab = smem + (buf << 15);
        const short* bb = ab + 16384;
        bf16x8 a0[4], a1[4], b0[4], b1[4];
        DSRA(a0, 0, 0); DSRB(b0, 0);
        bar_raw(); LGKM0; SB;
        MFMA16(a0, b0, 0);
        SB; bar_raw();
        DSRA(a1, 1, 0);
        WAITVM(0);
        bar_raw(); LGKM0; SB;
        MFMA16(a1, b0, 1);
        SB; bar_raw();
        DSRA(a0, 0, 1); DSRB(b1, 1);
        bar_raw(); LGKM0; SB;
        MFMA16(a0, b1, 0);
        SB; bar_raw();
        DSRA(a1, 1, 1);
        bar_raw(); LGKM0; SB;
        MFMA16(a1, b1, 1);
        SB;
    }
#undef STAGE_A
#undef STAGE_B
#undef DSRA
#undef DSRB
#undef MFMA16

    // C/D layout: col = lane&15, row = (lane>>4)*4 + reg
    int cn = lane & 15, cm = kq * 4;
    int mbase = row0 + wm * 128, nbase = col0 + wn * 64;
    if (Cb) {
#pragma unroll
        for (int j = 0; j < 4; j++) {
            int n = nbase + j * 16 + cn;
            if (n >= ldc) continue;
            bool real = (n % nmod) < N;
            float bvv = (real && bias) ? bias[n] : 0.f;
#pragma unroll
            for (int i = 0; i < 8; i++) {
#pragma unroll
                for (int r = 0; r < 4; r++) {
                    int m = mbase + i * 16 + cm + r;
                    float c = real ? alpha * acc[i][j][r] + bvv : 0.f;
                    if (act) c = fmaxf(c, 0.f);
                    Cb[(size_t)m * ldc + n] = __float2bfloat16(c);
                }
            }
        }
    } else {
#pragma unroll
        for (int j = 0; j < 4; j++) {
            int n = nbase + j * 16 + cn;
            if (n >= N) continue;
            float bvv = bias ? bias[n] : 0.f;
#pragma unroll
            for (int i = 0; i < 8; i++) {
#pragma unroll
                for (int r = 0; r < 4; r++) {
                    int m = mbase + i * 16 + cm + r;
                    float c = alpha * acc[i][j][r] + bvv;
                    if (act) c = fmaxf(c, 0.f);
                    Cf[(size_t)m * ldc + n] = c;
                }
            }
        }
    }
    // fused BN column partials (fp32-out path): LDS tree-reduce, ps[by][n] unique.
    if (!Cb && psOut) {
        float cs2v[4], cs1v[4];
#pragma unroll
        for (int j = 0; j < 4; j++) { cs1v[j] = 0.f; cs2v[j] = 0.f; }
#pragma unroll
        for (int j = 0; j < 4; j++) {
            int n = nbase + j * 16 + cn;
            if (n >= N) continue;
            float bvv = bias ? bias[n] : 0.f;
#pragma unroll
            for (int i = 0; i < 8; i++) {
#pragma unroll
                for (int r = 0; r < 4; r++) {
                    float c = alpha * acc[i][j][r] + bvv;
                    if (act) c = fmaxf(c, 0.f);
                    cs1v[j] += c;
                    cs2v[j] += c * c;
                }
            }
        }
        bar_raw();
        float* red = (float*)smem;  // 2 x 2048 floats = 16 KB
        int pid = wm * 4 + kq;
#pragma unroll
        for (int j = 0; j < 4; j++) {
            int slot = wn * 64 + j * 16 + cn;
            red[pid * 256 + slot] = cs1v[j];
            red[2048 + pid * 256 + slot] = cs2v[j];
        }
        bar_raw();
        if (wm == 0 && kq == 0) {
#pragma unroll
            for (int j = 0; j < 4; j++) {
                int slot = wn * 64 + j * 16 + cn;
                float s = 0.f, s2 = 0.f;
#pragma unroll
                for (int p = 0; p < 8; p++) {
                    s += red[p * 256 + slot];
                    s2 += red[2048 + p * 256 + slot];
                }
                int n = col0 + slot;
                if (n < N) {
                    psOut[(size_t)by * N + n] = s;
                    ps2Out[(size_t)by * N + n] = s2;
                }
            }
        }
    }
}

// ---------------- BatchNorm finalize (partials fp32, from GEMM epilogue) ----------------
__global__ void bn_finalize_k(const float* __restrict__ ps, const float* __restrict__ ps2,
                              const float* __restrict__ g, const float* __restrict__ b,
                              float* __restrict__ scale, float* __restrict__ shift,
                              int Ncol, int nParts, int M) {
    int c = blockIdx.x * 256 + threadIdx.x;
    if (c >= Ncol) return;
    double s = 0, s2 = 0;
    for (int p = 0; p < nParts; p++) {
        s += ps[(size_t)p * Ncol + c];
        s2 += ps2[(size_t)p * Ncol + c];
    }
    double m = s / M;
    double v = s2 / M - m * m;
    float sc = g[c] / sqrtf((float)v + EPSV);
    scale[c] = sc;
    shift[c] = b[c] - (float)m * sc;
}

// BN apply + leaky -> bf16 [M][Cpad] (+ optional fp32 out [M][Nreal])
__global__ void bn_apply_k(const float* __restrict__ X, const float* __restrict__ scale,
                           const float* __restrict__ shift, __hip_bfloat16* __restrict__ Yb,
                           float* __restrict__ Yf, int Nreal, int Cpad) {
    int c = blockIdx.x * 256 + threadIdx.x;
    int r = blockIdx.y;
    if (c >= Cpad) return;
    float v = 0.f;
    if (c < Nreal) {
        v = fmaf(X[(size_t)r * Nreal + c], scale[c], shift[c]);
        v = v >= 0.f ? v : SLOPEV * v;
        if (Yf) Yf[(size_t)r * Nreal + c] = v;
    }
    Yb[(size_t)r * Cpad + c] = __float2bfloat16(v);
}

// ---------------- reductions ----------------
__device__ __forceinline__ double wave_sum_d(double v) {
#pragma unroll
    for (int o = 32; o > 0; o >>= 1) v += __shfl_down(v, o, 64);
    return v;
}
__device__ __forceinline__ float wave_sum_f(float v) {
#pragma unroll
    for (int o = 32; o > 0; o >>= 1) v += __shfl_down(v, o, 64);
    return v;
}
__device__ __forceinline__ float wave_max_f(float v) {
#pragma unroll
    for (int o = 32; o > 0; o >>= 1) v = fmaxf(v, __shfl_down(v, o, 64));
    return v;
}

// LayerNorm + leaky: fp32 [4096][2500] -> bf16 into A4cat cols [0,2500), pad [5000,KP4)
__global__ __launch_bounds__(256) void ln_leaky_k(const float* __restrict__ X,
                                                  const float* __restrict__ g,
                                                  const float* __restrict__ b,
                                                  __hip_bfloat16* __restrict__ A4) {
    int row = blockIdx.x;
    const float* xr = X + (size_t)row * DH;
    double s = 0, s2 = 0;
    for (int c = threadIdx.x; c < DH; c += 256) {
        float x = xr[c];
        s += x;
        s2 += (double)x * x;
    }
    __shared__ double sb[4], sb2[4];
    int lane = threadIdx.x & 63, w = threadIdx.x >> 6;
    s = wave_sum_d(s);
    s2 = wave_sum_d(s2);
    if (lane == 0) { sb[w] = s; sb2[w] = s2; }
    __syncthreads();
    double S = sb[0] + sb[1] + sb[2] + sb[3];
    double S2 = sb2[0] + sb2[1] + sb2[2] + sb2[3];
    double m = S / DH;
    double v = S2 / DH - m * m;
    float inv = 1.f / sqrtf((float)v + EPSV);
    float mf = (float)m;
    __hip_bfloat16* yr = A4 + (size_t)row * KP4;
    for (int c = threadIdx.x; c < DH; c += 256) {
        float x = (xr[c] - mf) * inv * g[c] + b[c];
        x = x >= 0.f ? x : SLOPEV * x;
        yr[c] = __float2bfloat16(x);
    }
    if (threadIdx.x < KP4 - KC4) yr[KC4 + threadIdx.x] = __float2bfloat16(0.f);
}

// single-pass softmax over 4096-wide rows: row in registers (16 f/thread)
__global__ __launch_bounds__(256) void softmax1_k(const float* __restrict__ X,
                                                  __hip_bfloat16* __restrict__ Y) {
    int row = blockIdx.x, t = threadIdx.x;
    const f32x4* xr = reinterpret_cast<const f32x4*>(X + (size_t)row * NTRAIN);
    f32x4 v[4];
    float mx = -3.4e38f;
#pragma unroll
    for (int i = 0; i < 4; i++) {
        v[i] = xr[i * 256 + t];
#pragma unroll
        for (int c = 0; c < 4; c++) mx = fmaxf(mx, v[i][c]);
    }
    __shared__ float sb[4];
    int lane = t & 63, w = t >> 6;
    mx = wave_max_f(mx);
    if (lane == 0) sb[w] = mx;
    __syncthreads();
    mx = fmaxf(fmaxf(sb[0], sb[1]), fmaxf(sb[2], sb[3]));
    float s = 0.f;
#pragma unroll
    for (int i = 0; i < 4; i++)
#pragma unroll
        for (int c = 0; c < 4; c++) {
            float e = expf(v[i][c] - mx);
            v[i][c] = e;
            s += e;
        }
    s = wave_sum_f(s);
    __syncthreads();  // sb reuse
    if (lane == 0) sb[w] = s;
    __syncthreads();
    float inv = 1.f / (sb[0] + sb[1] + sb[2] + sb[3]);
    ushort4* yr = reinterpret_cast<ushort4*>(Y + (size_t)row * NTRAIN);
#pragma unroll
    for (int i = 0; i < 4; i++) {
        ushort4 o;
        o.x = bfbits(v[i][0] * inv);
        o.y = bfbits(v[i][1] * inv);
        o.z = bfbits(v[i][2] * inv);
        o.w = bfbits(v[i][3] * inv);
        yr[i * 256 + t] = o;
    }
}

// final tiny GEMM: Y[4096][16] = X[4096][2500] @ Wce[2500][16] + bce
__global__ __launch_bounds__(256) void head_k(const float* __restrict__ X,
                                              const float* __restrict__ Wce,
                                              const float* __restrict__ bce,
                                              float* __restrict__ Y) {
    int row = blockIdx.x;
    int n = threadIdx.x & 15, part = threadIdx.x >> 4;
    const float* xr = X + (size_t)row * DH;
    float s = 0.f;
    for (int k = part; k < DH; k += 16) s += xr[k] * Wce[k * 16 + n];
    __shared__ float red[256];
    red[threadIdx.x] = s;
    __syncthreads();
    for (int off = 8; off >= 1; off >>= 1) {
        if (part < off) red[threadIdx.x] += red[threadIdx.x + off * 16];
        __syncthreads();
    }
    if (part == 0) Y[row * 16 + n] = red[n] + bce[n];
}

// ---------------- launch ----------------
extern "C" void kernel_launch(void* const* d_in, const int* in_sizes, int n_in,
                              void* d_out, int out_size, void* d_ws, size_t ws_size,
                              hipStream_t stream) {
    const float* gene    = (const float*)d_in[0];
    const float* trainf  = (const float*)d_in[1];
    const float* yhat    = (const float*)d_in[2];
    const int*   esrc    = (const int*)d_in[3];
    const int*   edst    = (const int*)d_in[4];
    const float* W_self3 = (const float*)d_in[5];
    const float* W_neigh3= (const float*)d_in[6];
    const float* b3      = (const float*)d_in[7];
    const float* bn3_g   = (const float*)d_in[8];
    const float* bn3_b   = (const float*)d_in[9];
    const float* Wq      = (const float*)d_in[10];
    const float* Wk      = (const float*)d_in[11];
    const float* Wv      = (const float*)d_in[12];
    const float* bq      = (const float*)d_in[13];
    const float* bk      = (const float*)d_in[14];
    const float* bv      = (const float*)d_in[15];
    const float* Wo      = (const float*)d_in[16];
    const float* bo      = (const float*)d_in[17];
    const float* ln2_g   = (const float*)d_in[18];
    const float* ln2_b   = (const float*)d_in[19];
    const float* W_self4 = (const float*)d_in[20];
    const float* W_neigh4= (const float*)d_in[21];
    const float* b4      = (const float*)d_in[22];
    const float* bn4_g   = (const float*)d_in[23];
    const float* bn4_b   = (const float*)d_in[24];
    const float* W_lin2  = (const float*)d_in[25];
    const float* b_lin2  = (const float*)d_in[26];
    const float* W_ce    = (const float*)d_in[27];
    const float* b_ce    = (const float*)d_in[28];

    char* ws = (char*)d_ws;
    size_t off = 0;
    auto alloc = [&](size_t bytes) -> void* {
        void* p = ws + off;
        off = (off + bytes + 255) & ~(size_t)255;
        return p;
    };
    __hip_bfloat16* A3cat  = (__hip_bfloat16*)alloc((size_t)NTRAIN * KP3 * 2);   // also attn_bf
    __hip_bfloat16* A4cat  = (__hip_bfloat16*)alloc((size_t)NTRAIN * KP4 * 2);
    __hip_bfloat16* h_bf   = (__hip_bfloat16*)alloc((size_t)NTRAIN * KPH * 2);   // also xhat_bf
    __hip_bfloat16* qkv_bf = (__hip_bfloat16*)alloc((size_t)NTRAIN * NQKV * 2);  // also ao_bf
    __hip_bfloat16* W3t    = (__hip_bfloat16*)alloc((size_t)NPW * KP3 * 2);      // also W4t
    __hip_bfloat16* Wqkvt  = (__hip_bfloat16*)alloc((size_t)3 * NPW * KPH * 2);  // also Wot/Wlin2t
    float*  bigC   = (float*)alloc((size_t)NTRAIN * NTRAIN * 4);                 // also vT_bf
    float*  ps     = (float*)alloc((size_t)16 * DH * 4);
    float*  ps2    = (float*)alloc((size_t)16 * DH * 4);
    float*  scale  = (float*)alloc(DH * 4);
    float*  shift  = (float*)alloc(DH * 4);
    float*  bqkv   = (float*)alloc(NQKV * 4);
    int*    deg    = (int*)alloc(NTRAIN * 4);
    int*    indptr = (int*)alloc((NTRAIN + 1) * 4);
    int*    cursor = (int*)alloc(NTRAIN * 4);
    int*    csr_src= (int*)alloc(NEDGES * 4);
    __hip_bfloat16* attn_bf = A3cat;   // [4096][4096] (A3cat dead after conv3)
    __hip_bfloat16* W4t     = W3t;     // after conv3 gemm
    __hip_bfloat16* Wot     = Wqkvt;   // after qkv gemm
    __hip_bfloat16* Wlin2t  = Wqkvt;   // after Wo gemm
    __hip_bfloat16* xhat_bf = h_bf;    // h_bf dead after qkv gemm
    __hip_bfloat16* ao_bf   = qkv_bf;  // q/k/v dead after scores+vT
    __hip_bfloat16* vT_bf   = (__hip_bfloat16*)bigC;  // built after softmax, dead before Wo gemm
    // gene_bf (100.2 MB) aliases W3t+Wqkvt+bigC span (133 MB): dead before wtrans W3t
    short* gene_bf = (short*)W3t;

    float* xhat = (float*)d_out;                       // [4096][2500]
    float* yout = (float*)d_out + (size_t)NTRAIN * DH; // [4096][16]

    // gemm launcher; optional aux transpose jobs ride on the idle CUs of 160-block grids
    auto gemm = [&](const void* A, const void* Bt, const float* bias, float* Cf,
                    __hip_bfloat16* Cb, float* psO, float* ps2O, int NpadCols, int Nreal,
                    int K, int sA, int sB, int ldc, int nmod, float alpha, int act,
                    const float* x0, const float* x1, const float* x2, const float* x3,
                    const float* x4, const float* x5, short* xout, long xstride,
                    int xldw, int xNreal, int xK1, int xK12, int xKpad, int xNpad, int nslab) {
        int gx = NpadCols / 256, gy = NTRAIN / 256;
        int ngemm = gx * gy;
        int extraY = (nslab > 0) ? 9 : 0;  // +90 worker blocks (total 250 <= 256 CUs)
        dim3 g(gx, gy + extraY);
        gemm256_k<<<g, 512, 0, stream>>>((const short*)A, (const short*)Bt, bias, Cf, Cb,
                                         psO, ps2O, Nreal, K, sA, sB, ldc, nmod, alpha, act,
                                         ngemm, x0, x1, x2, x3, x4, x5, xout, xstride,
                                         xldw, xNreal, xK1, xK12, xKpad, xNpad, nslab);
    };
    const float* Z = nullptr;

    // ---- CSR + bf16 gene + neighbor mean ----
    hipMemsetAsync(deg, 0, NTRAIN * 4, stream);
    count_deg_k<<<NEDGES / 256, 256, 0, stream>>>(edst, deg);
    scan_deg_k<<<1, 1024, 0, stream>>>(deg, indptr, cursor);
    scatter_edges_k<<<NEDGES / 256, 256, 0, stream>>>(esrc, edst, cursor, csr_src);
    gene2bf_k<<<dim3(2, 20000), 256, 0, stream>>>(gene, gene_bf);
    sage_mean_k<<<NTRAIN, 256, 0, stream>>>(gene_bf, indptr, csr_src, A3cat, A4cat);
    dst_build_k<<<dim3((KP3 + 255) / 256, NTRAIN), 256, 0, stream>>>(trainf, yhat, A3cat);
    // W3t = [W_self3; W_neigh3]^T -> [2560][5184] (overwrites gene_bf region: sage done)
    wtrans_k<<<dim3(KP3 / 32, NPW / 32), 256, 0, stream>>>(W_self3, W_neigh3, DH, W3t, DH, 2675, KC3, KP3, NPW);

    // ---- conv3 (K=5184 GEMM, BN partials fused; FAT: Wq/Wk/Wv -> Wqkvt) ----
    gemm(A3cat, W3t, b3, bigC, nullptr, ps, ps2, NPW, DH, KP3, KP3, KP3, DH, DH, 1.f, 0,
         Wq, Z, Wk, Z, Wv, Z, (short*)Wqkvt, (long)NPW * KPH, DH, DH, DH, DH, KPH, NPW, 3);
    bn_finalize_k<<<(DH + 255) / 256, 256, 0, stream>>>(ps, ps2, bn3_g, bn3_b, scale, shift, DH, 16, NTRAIN);
    bn_apply_k<<<dim3((KPH + 255) / 256, NTRAIN), 256, 0, stream>>>(bigC, scale, shift, h_bf, nullptr, DH, KPH);

    // ---- attention ----
    qkv_bias_k<<<NQKV / 256, 256, 0, stream>>>(bq, bk, bv, bqkv);
    // fused qkv: [4096][7680] bf16, grid 30x16=480 blocks (full — no fat)
    gemm(h_bf, Wqkvt, bqkv, nullptr, qkv_bf, nullptr, nullptr, NQKV, DH, KPH, KPH, KPH, NQKV, KPH, 1.f, 0,
         Z, Z, Z, Z, Z, Z, nullptr, 0, 0, 0, 0, 0, 32, 32, 0);
    // scores = q @ k^T * (1/50) -> bigC [4096][4096] (256 blocks — full)
    gemm(qkv_bf, qkv_bf + KPH, nullptr, bigC, nullptr, nullptr, nullptr, NTRAIN, NTRAIN, KPH, NQKV, NQKV, NTRAIN, NTRAIN, 0.02f, 0,
         Z, Z, Z, Z, Z, Z, nullptr, 0, 0, 0, 0, 0, 32, 32, 0);
    softmax1_k<<<NTRAIN, 256, 0, stream>>>(bigC, attn_bf);
    // vT = v^T -> bf16 [2560][4096] (into bigC alias; scores dead after softmax)
    btrans_k<<<dim3(NTRAIN / 32, KPH / 32), 256, 0, stream>>>(qkv_bf + 2 * KPH, NQKV, vT_bf);
    // attn @ v -> bf16 ao_bf (FAT: Wo -> Wot; Wqkvt readers done)
    gemm(attn_bf, vT_bf, nullptr, nullptr, ao_bf, nullptr, nullptr, NPW, DH, NTRAIN, NTRAIN, NTRAIN, KPH, KPH, 1.f, 0,
         Wo, Z, Z, Z, Z, Z, (short*)Wot, 0, DH, DH, DH, DH, KPH, NPW, 1);
    // @ Wo + bo -> bigC (FAT: [W_self4;W_neigh4] -> W4t; W3t reader done)
    gemm(ao_bf, Wot, bo, bigC, nullptr, nullptr, nullptr, NPW, DH, KPH, KPH, KPH, DH, DH, 1.f, 0,
         W_self4, W_neigh4, Z, Z, Z, Z, (short*)W4t, 0, DH, DH, DH, KC4, KP4, NPW, 1);
    ln_leaky_k<<<NTRAIN, 256, 0, stream>>>(bigC, ln2_g, ln2_b, A4cat);

    // ---- conv4 (K=5056 GEMM, BN partials fused; FAT: W_lin2 -> Wlin2t; Wot reader done) ----
    gemm(A4cat, W4t, b4, bigC, nullptr, ps, ps2, NPW, DH, KP4, KP4, KP4, DH, DH, 1.f, 0,
         W_lin2, Z, Z, Z, Z, Z, (short*)Wlin2t, 0, DH, DH, DH, DH, KPH, NPW, 1);
    bn_finalize_k<<<(DH + 255) / 256, 256, 0, stream>>>(ps, ps2, bn4_g, bn4_b, scale, shift, DH, 16, NTRAIN);
    bn_apply_k<<<dim3((KPH + 255) / 256, NTRAIN), 256, 0, stream>>>(bigC, scale, shift, xhat_bf, xhat, DH, KPH);

    // ---- head ----
    gemm(xhat_bf, Wlin2t, b_lin2, bigC, nullptr, nullptr, nullptr, NPW, DH, KPH, KPH, KPH, DH, DH, 1.f, 1,
         Z, Z, Z, Z, Z, Z, nullptr, 0, 0, 0, 0, 0, 32, 32, 0);  // relu
    head_k<<<NTRAIN, 256, 0, stream>>>(bigC, W_ce, b_ce, yout);
    (void)ws_size; (void)n_in; (void)in_sizes; (void)out_size;
}

// Round 12
// 1666.757 us; speedup vs baseline: 1.1451x; 1.1451x over previous
//
#include <hip/hip_runtime.h>
#include <hip/hip_bf16.h>
#include <cstdint>
#include <cstddef>

constexpr int NTRAIN = 4096;
constexpr int NEDGES = 131072;
constexpr int DSRC = 2500, DH = 2500, DNC = 16;
constexpr int KD1 = 2659;   // trainf cols
constexpr int KC3 = 5175;   // conv3 cat K real (2675 + 2500)
constexpr int KP3 = 5184;   // conv3 cat K padded (81*64)
constexpr int KC4 = 5000;   // conv4 cat K real
constexpr int KP4 = 5056;   // conv4 cat K padded (79*64)
constexpr int KPH = 2560;   // 2500 padded to mult of 64 (40*64)
constexpr int NPW = 2560;   // 2500 padded to mult of 256
constexpr int NQKV = 7680;  // 3*2560 fused qkv width
constexpr int GSTR = 2504;  // bf16 gene row stride (313*8)
constexpr float EPSV = 1e-5f;
constexpr float SLOPEV = 0.01f;

typedef __attribute__((ext_vector_type(8))) short bf16x8;
typedef __attribute__((ext_vector_type(4))) float f32x4;

static __device__ __forceinline__ unsigned short bfbits(float f) {
    __hip_bfloat16 h = __float2bfloat16(f);
    return *reinterpret_cast<unsigned short*>(&h);
}
static __device__ __forceinline__ float b2f(short s) {
    return __uint_as_float(((unsigned)(unsigned short)s) << 16);
}

// ---------------- CSR build ----------------
__global__ void count_deg_k(const int* __restrict__ edst, int* __restrict__ deg) {
    int e = blockIdx.x * 256 + threadIdx.x;
    if (e < NEDGES) atomicAdd(&deg[edst[e]], 1);
}

__global__ __launch_bounds__(1024) void scan_deg_k(const int* __restrict__ deg,
                                                   int* __restrict__ indptr,
                                                   int* __restrict__ cursor) {
    __shared__ int sums[1024];
    int t = threadIdx.x;
    int base = t * 4;
    int d0 = deg[base + 0], d1 = deg[base + 1], d2 = deg[base + 2], d3 = deg[base + 3];
    sums[t] = d0 + d1 + d2 + d3;
    __syncthreads();
    for (int o = 1; o < 1024; o <<= 1) {
        int v = (t >= o) ? sums[t - o] : 0;
        __syncthreads();
        sums[t] += v;
        __syncthreads();
    }
    int excl = (t == 0) ? 0 : sums[t - 1];
    int p0 = excl, p1 = p0 + d0, p2 = p1 + d1, p3 = p2 + d2;
    indptr[base + 0] = p0; indptr[base + 1] = p1; indptr[base + 2] = p2; indptr[base + 3] = p3;
    cursor[base + 0] = p0; cursor[base + 1] = p1; cursor[base + 2] = p2; cursor[base + 3] = p3;
    if (t == 1023) indptr[4096] = p3 + d3;
}

__global__ void scatter_edges_k(const int* __restrict__ esrc, const int* __restrict__ edst,
                                int* __restrict__ cursor, int* __restrict__ csr_src) {
    int e = blockIdx.x * 256 + threadIdx.x;
    if (e < NEDGES) {
        int d = edst[e];
        int p = atomicAdd(&cursor[d], 1);
        csr_src[p] = esrc[e];
    }
}

// fp32 gene [20000][2500] -> bf16 [20000][GSTR] (cols 2500..2503 zeroed)
__global__ __launch_bounds__(256) void gene2bf_k(const float* __restrict__ gene,
                                                 short* __restrict__ gbf) {
    int v = blockIdx.x * 256 + threadIdx.x;
    if (v >= 313) return;
    int row = blockIdx.y;
    const float* src = gene + (size_t)row * DSRC + v * 8;
    f32x4 a = *(const f32x4*)(src);
    f32x4 b = {0.f, 0.f, 0.f, 0.f};
    if (v < 312) b = *(const f32x4*)(src + 4);
    bf16x8 o;
#pragma unroll
    for (int c = 0; c < 4; c++) o[c] = (short)bfbits(a[c]);
#pragma unroll
    for (int c = 0; c < 4; c++) o[4 + c] = (short)bfbits(b[c]);
    *(bf16x8*)(gbf + (size_t)row * GSTR + v * 8) = o;
}

// neighbor mean over bf16 gene table; writes bf16 into BOTH concat-A buffers.
__global__ __launch_bounds__(256) void sage_mean_k(const short* __restrict__ gbf,
                                                   const int* __restrict__ indptr,
                                                   const int* __restrict__ csr_src,
                                                   __hip_bfloat16* __restrict__ A3,
                                                   __hip_bfloat16* __restrict__ A4) {
    int row = blockIdx.x;
    int s = indptr[row], e = indptr[row + 1];
    int t = threadIdx.x;
    float a0[8], a1[8];
#pragma unroll
    for (int c = 0; c < 8; c++) { a0[c] = 0.f; a1[c] = 0.f; }
    bool has1 = (t < 57);  // t+256 < 313
    int j = s;
    for (; j + 2 <= e; j += 2) {
        const bf16x8* g0 = (const bf16x8*)(gbf + (size_t)csr_src[j] * GSTR);
        const bf16x8* g1 = (const bf16x8*)(gbf + (size_t)csr_src[j + 1] * GSTR);
        bf16x8 u0 = g0[t], w0 = g1[t];
        bf16x8 u1, w1;
        if (has1) { u1 = g0[t + 256]; w1 = g1[t + 256]; }
#pragma unroll
        for (int c = 0; c < 8; c++) a0[c] += b2f(u0[c]) + b2f(w0[c]);
        if (has1) {
#pragma unroll
            for (int c = 0; c < 8; c++) a1[c] += b2f(u1[c]) + b2f(w1[c]);
        }
    }
    if (j < e) {
        const bf16x8* g0 = (const bf16x8*)(gbf + (size_t)csr_src[j] * GSTR);
        bf16x8 u0 = g0[t];
#pragma unroll
        for (int c = 0; c < 8; c++) a0[c] += b2f(u0[c]);
        if (has1) {
            bf16x8 u1 = g0[t + 256];
#pragma unroll
            for (int c = 0; c < 8; c++) a1[c] += b2f(u1[c]);
        }
    }
    float inv = 1.f / fmaxf((float)(e - s), 1.f);
#pragma unroll
    for (int c = 0; c < 8; c++) {
        int f = t * 8 + c;  // < 2048
        __hip_bfloat16 h = __float2bfloat16(a0[c] * inv);
        A3[(size_t)row * KP3 + 2675 + f] = h;
        A4[(size_t)row * KP4 + 2500 + f] = h;
    }
    if (has1) {
#pragma unroll
        for (int c = 0; c < 8; c++) {
            int f = (t + 256) * 8 + c;
            if (f < 2500) {
                __hip_bfloat16 h = __float2bfloat16(a1[c] * inv);
                A3[(size_t)row * KP3 + 2675 + f] = h;
                A4[(size_t)row * KP4 + 2500 + f] = h;
            }
        }
    }
}

// build [trainf | yhat] part of conv3 concat A (cols [0,2675) and pad [5175,5184))
__global__ void dst_build_k(const float* __restrict__ trainf, const float* __restrict__ yhat,
                            __hip_bfloat16* __restrict__ A3) {
    int c = blockIdx.x * 256 + threadIdx.x;
    int r = blockIdx.y;
    if (c >= KP3) return;
    if (c >= 2675 && c < KC3) return;  // sage_mean's region
    float v = 0.f;
    if (c < KD1) v = trainf[(size_t)r * KD1 + c];
    else if (c < 2675) v = yhat[r * DNC + (c - KD1)];
    A3[(size_t)r * KP3 + c] = __float2bfloat16(v);
}

// transpose (optionally 2-source concat along k) fp32 [K][Nreal] -> bf16 [Npad][Kpad]
__global__ __launch_bounds__(256) void wtrans_k(const float* __restrict__ W1,
                                                const float* __restrict__ W2, int ldw,
                                                __hip_bfloat16* __restrict__ Wt,
                                                int Nreal, int K1, int K12, int Kpad, int Npad) {
    __shared__ float tile[32][33];
    int k0 = blockIdx.x * 32, n0 = blockIdx.y * 32;
    int x = threadIdx.x & 31, y = threadIdx.x >> 5;
#pragma unroll
    for (int i = 0; i < 32; i += 8) {
        int k = k0 + y + i, n = n0 + x;
        float v = 0.f;
        if (n < Nreal) {
            if (k < K1) v = W1[(size_t)k * ldw + n];
            else if (k < K12) v = W2[(size_t)(k - K1) * ldw + n];
        }
        tile[y + i][x] = v;
    }
    __syncthreads();
#pragma unroll
    for (int i = 0; i < 32; i += 8) {
        int n = n0 + y + i, k = k0 + x;
        if (n < Npad && k < Kpad) Wt[(size_t)n * Kpad + k] = __float2bfloat16(tile[x][y + i]);
    }
}

// 3-slab variant: blockIdx.z selects {Wq,Wk,Wv} -> Wqkvt + z*NPW*KPH (one dispatch,
// each slab still gets 6400 fully-parallel blocks — R11's fat-launch aux loop was
// latency-serialized at 90 workers; this keeps the proven full-fill shape).
__global__ __launch_bounds__(256) void wtrans3_k(const float* __restrict__ Wq,
                                                 const float* __restrict__ Wk,
                                                 const float* __restrict__ Wv,
                                                 __hip_bfloat16* __restrict__ Wqkvt) {
    __shared__ float tile[32][33];
    const float* W1 = (blockIdx.z == 0) ? Wq : (blockIdx.z == 1) ? Wk : Wv;
    __hip_bfloat16* Wt = Wqkvt + (size_t)blockIdx.z * NPW * KPH;
    int k0 = blockIdx.x * 32, n0 = blockIdx.y * 32;
    int x = threadIdx.x & 31, y = threadIdx.x >> 5;
#pragma unroll
    for (int i = 0; i < 32; i += 8) {
        int k = k0 + y + i, n = n0 + x;
        float v = 0.f;
        if (n < DH && k < DH) v = W1[(size_t)k * DH + n];
        tile[y + i][x] = v;
    }
    __syncthreads();
#pragma unroll
    for (int i = 0; i < 32; i += 8) {
        int n = n0 + y + i, k = k0 + x;
        Wt[(size_t)n * KPH + k] = __float2bfloat16(tile[x][y + i]);
    }
}

// bf16 [4096][cols @ ldv] -> bf16 [2560][4096] transpose (v -> vT)
__global__ __launch_bounds__(256) void btrans_k(const __hip_bfloat16* __restrict__ V, int ldv,
                                                __hip_bfloat16* __restrict__ VT) {
    __shared__ __hip_bfloat16 tile[32][33];
    int r0 = blockIdx.x * 32, c0 = blockIdx.y * 32;
    int x = threadIdx.x & 31, y = threadIdx.x >> 5;
#pragma unroll
    for (int i = 0; i < 32; i += 8)
        tile[y + i][x] = V[(size_t)(r0 + y + i) * ldv + c0 + x];
    __syncthreads();
#pragma unroll
    for (int i = 0; i < 32; i += 8)
        VT[(size_t)(c0 + y + i) * NTRAIN + r0 + x] = tile[x][y + i];
}

// concat bias [bq|bk|bv] -> [7680] with zero pads
__global__ void qkv_bias_k(const float* __restrict__ bq, const float* __restrict__ bk,
                           const float* __restrict__ bv, float* __restrict__ bqkv) {
    int i = blockIdx.x * 256 + threadIdx.x;
    if (i >= NQKV) return;
    int j = i / KPH, c = i % KPH;
    const float* src = (j == 0) ? bq : (j == 1) ? bk : bv;
    bqkv[i] = (c < DH) ? src[c] : 0.f;
}

// ---------------- 256x256 8-phase MFMA bf16 GEMM (R3/R8 exact — best measured) ----------------
// C[M,N] = alpha*A[M,K]@Bt[N,K]^T (+bias)(+relu); out fp32 (Cf) or bf16 (Cb, cols with
// (n % nmod) >= N zero-filled). BK=64, 8 waves (2Mx4N), double-buffered 128KB LDS,
// st_16x32 swizzle. Per K-tile: 4 phases, counted vmcnt(4) at phases 1/3.
// Fused BN column-partials (psOut!=null, fp32-out path): ps[by][n], grid.y=16 partition.
// EXPLORED-AND-REJECTED (measured, do not retry):
//  - runtime-slot 4-ring (R4-R6): regalloc cliff, 5.5 GB scratch, 8x slower.
//  - merged 32-MFMA phases (R7): 38->33% MfmaUtil.
//  - static 4-slot deep pipeline, vmcnt(8) (R9): clean codegen but 181->195us — stall is
//    the barrier-lockstep LDS<->MFMA alternation; R3's exact 4-phase shape is optimal.
//  - fat launches with aux transpose riders (R11): aux loop latency-serialized at 90
//    workers (213 sync-gated iterations ~ 300us) -> dispatch = max(GEMM, aux), +235us.
__device__ __forceinline__ void async_cp16(const void* g, void* l) {
    __builtin_amdgcn_global_load_lds((const __attribute__((address_space(1))) void*)g,
                                     (__attribute__((address_space(3))) void*)l, 16, 0, 0);
}
#define WAITVM(N) asm volatile("s_waitcnt vmcnt(" #N ")" ::: "memory")
#define LGKM0 asm volatile("s_waitcnt lgkmcnt(0)" ::: "memory")
#define SB __builtin_amdgcn_sched_barrier(0)
static __device__ __forceinline__ void bar_raw() {
    asm volatile("" ::: "memory");
    __builtin_amdgcn_s_barrier();
    asm volatile("" ::: "memory");
}

__global__ __launch_bounds__(512, 2) void gemm256_k(const short* __restrict__ A,
                                                    const short* __restrict__ Bt,
                                                    const float* __restrict__ bias,
                                                    float* __restrict__ Cf,
                                                    __hip_bfloat16* __restrict__ Cb,
                                                    float* __restrict__ psOut,
                                                    float* __restrict__ ps2Out,
                                                    int N, int K, int sA, int sB, int ldc,
                                                    int nmod, float alpha, int act) {
    __shared__ short smem[65536];  // [buf][A 32KB | B 32KB]; reused as fp32 scratch in epilogue
    // bijective XCD swizzle
    int nwg = gridDim.x * gridDim.y;
    int orig = blockIdx.y * gridDim.x + blockIdx.x;
    int qd = nwg >> 3, rr = nwg & 7;
    int xcd = orig & 7, oidx = orig >> 3;
    int nb = (xcd < rr ? xcd * (qd + 1) : rr * (qd + 1) + (xcd - rr) * qd) + oidx;
    int bx = nb % gridDim.x, by = nb / gridDim.x;
    int row0 = by * 256, col0 = bx * 256;

    int tid = threadIdx.x;
    int wave = tid >> 6, lane = tid & 63;
    int wm = wave >> 2, wn = wave & 3;

    // staging: per-lane inverse-swizzled source; LDS dest = subtile base + lane*16
    int rsub = lane >> 2;
    int cs = ((lane & 3) * 8) ^ ((lane >= 32) ? 16 : 0);
    const short* gA0 = A + (size_t)(row0 + wave * 16 + rsub) * sA + cs;
    const short* gA1 = A + (size_t)(row0 + wave * 16 + 128 + rsub) * sA + cs;
    const short* gB0 = Bt + (size_t)(col0 + wave * 16 + rsub) * sB + cs;
    const short* gB1 = Bt + (size_t)(col0 + wave * 16 + 128 + rsub) * sB + cs;
    int sa0 = wave * 1024;         // subtile (rb=wave, kb=0) base, shorts
    int sa1 = (wave + 8) * 1024;   // subtile (rb=wave+8, kb=0)

    // swizzled ds_read offset within subtile (shorts)
    int fr = lane & 15, kq = lane >> 4;
    int roff = fr * 32 + ((kq * 8) ^ ((fr & 8) ? 16 : 0));

    f32x4 acc[8][4];
#pragma unroll
    for (int i = 0; i < 8; i++)
#pragma unroll
        for (int j = 0; j < 4; j++)
#pragma unroll
            for (int r = 0; r < 4; r++) acc[i][j][r] = 0.f;

#define STAGE_A(kb, b, k0s) { \
    short* l0 = smem + (b) * 32768 + sa0 + (kb) * 512; \
    short* l1 = smem + (b) * 32768 + sa1 + (kb) * 512; \
    async_cp16(gA0 + (k0s) + (kb) * 32, l0); \
    async_cp16(gA1 + (k0s) + (kb) * 32, l1); }
#define STAGE_B(kb, b, k0s) { \
    short* l0 = smem + (b) * 32768 + 16384 + sa0 + (kb) * 512; \
    short* l1 = smem + (b) * 32768 + 16384 + sa1 + (kb) * 512; \
    async_cp16(gB0 + (k0s) + (kb) * 32, l0); \
    async_cp16(gB1 + (k0s) + (kb) * 32, l1); }
#define DSRA(dst, mq, kk) \
    _Pragma("unroll") for (int i = 0; i < 4; i++) \
        dst[i] = *(const bf16x8*)(ab + (((wm * 8 + (mq) * 4 + i) * 2 + (kk)) << 9) + roff);
#define DSRB(dst, kk) \
    _Pragma("unroll") for (int j = 0; j < 4; j++) \
        dst[j] = *(const bf16x8*)(bb + (((wn * 4 + j) * 2 + (kk)) << 9) + roff);
#define MFMA16(av, bvv, mq) \
    __builtin_amdgcn_s_setprio(1); \
    _Pragma("unroll") for (int i = 0; i < 4; i++) \
        _Pragma("unroll") for (int j = 0; j < 4; j++) \
            acc[(mq) * 4 + i][j] = __builtin_amdgcn_mfma_f32_16x16x32_bf16(av[i], bvv[j], acc[(mq) * 4 + i][j], 0, 0, 0); \
    __builtin_amdgcn_s_setprio(0);

    int nt = K >> 6;
    // prologue: tile 0's 4 half-groups into buf0 (order AK0,BK0,AK1,BK1)
    STAGE_A(0, 0, 0); STAGE_B(0, 0, 0); STAGE_A(1, 0, 0); STAGE_B(1, 0, 0);
    WAITVM(4);   // AK0,BK0 landed; AK1,BK1 in flight
    bar_raw();
    int buf = 0;
    for (int t = 0; t < nt - 1; ++t) {
        const short* ab = smem + (buf << 15);
        const short* bb = ab + 16384;
        int k1 = (t + 1) << 6;
        bf16x8 a0[4], a1[4], b0[4], b1[4];
        // p0: reads K-half0; stages next tile's AK0
        DSRA(a0, 0, 0); DSRB(b0, 0);
        STAGE_A(0, buf ^ 1, k1);
        bar_raw(); LGKM0; SB;
        MFMA16(a0, b0, 0);
        SB; bar_raw();
        // p1: stages BK0; vmcnt drains this tile's AK1,BK1 (needed at p2)
        DSRA(a1, 1, 0);
        STAGE_B(0, buf ^ 1, k1);
        WAITVM(4);
        bar_raw(); LGKM0; SB;
        MFMA16(a1, b0, 1);
        SB; bar_raw();
        // p2: reads K-half1; stages AK1
        DSRA(a0, 0, 1); DSRB(b1, 1);
        STAGE_A(1, buf ^ 1, k1);
        bar_raw(); LGKM0; SB;
        MFMA16(a0, b1, 0);
        SB; bar_raw();
        // p3: stages BK1; vmcnt drains next tile's AK0,BK0 (needed at next p0)
        DSRA(a1, 1, 1);
        STAGE_B(1, buf ^ 1, k1);
        WAITVM(4);
        bar_raw(); LGKM0; SB;
        MFMA16(a1, b1, 1);
        SB; bar_raw();
        buf ^= 1;
    }
    {   // final tile: no staging; drain remaining loads before K-half1 reads
        const short* ab = smem + (buf << 15);
        const short* bb = ab + 16384;
        bf16x8 a0[4], a1[4], b0[4], b1[4];
        DSRA(a0, 0, 0); DSRB(b0, 0);
        bar_raw(); LGKM0; SB;
        MFMA16(a0, b0, 0);
        SB; bar_raw();
        DSRA(a1, 1, 0);
        WAITVM(0);
        bar_raw(); LGKM0; SB;
        MFMA16(a1, b0, 1);
        SB; bar_raw();
        DSRA(a0, 0, 1); DSRB(b1, 1);
        bar_raw(); LGKM0; SB;
        MFMA16(a0, b1, 0);
        SB; bar_raw();
        DSRA(a1, 1, 1);
        bar_raw(); LGKM0; SB;
        MFMA16(a1, b1, 1);
        SB;
    }
#undef STAGE_A
#undef STAGE_B
#undef DSRA
#undef DSRB
#undef MFMA16

    // C/D layout: col = lane&15, row = (lane>>4)*4 + reg
    int cn = lane & 15, cm = kq * 4;
    int mbase = row0 + wm * 128, nbase = col0 + wn * 64;
    if (Cb) {
#pragma unroll
        for (int j = 0; j < 4; j++) {
            int n = nbase + j * 16 + cn;
            if (n >= ldc) continue;
            bool real = (n % nmod) < N;
            float bvv = (real && bias) ? bias[n] : 0.f;
#pragma unroll
            for (int i = 0; i < 8; i++) {
#pragma unroll
                for (int r = 0; r < 4; r++) {
                    int m = mbase + i * 16 + cm + r;
                    float c = real ? alpha * acc[i][j][r] + bvv : 0.f;
                    if (act) c = fmaxf(c, 0.f);
                    Cb[(size_t)m * ldc + n] = __float2bfloat16(c);
                }
            }
        }
    } else {
#pragma unroll
        for (int j = 0; j < 4; j++) {
            int n = nbase + j * 16 + cn;
            if (n >= N) continue;
            float bvv = bias ? bias[n] : 0.f;
#pragma unroll
            for (int i = 0; i < 8; i++) {
#pragma unroll
                for (int r = 0; r < 4; r++) {
                    int m = mbase + i * 16 + cm + r;
                    float c = alpha * acc[i][j][r] + bvv;
                    if (act) c = fmaxf(c, 0.f);
                    Cf[(size_t)m * ldc + n] = c;
                }
            }
        }
    }
    // fused BN column partials (fp32-out path): LDS tree-reduce, ps[by][n] unique.
    if (!Cb && psOut) {
        float cs1v[4], cs2v[4];
#pragma unroll
        for (int j = 0; j < 4; j++) { cs1v[j] = 0.f; cs2v[j] = 0.f; }
#pragma unroll
        for (int j = 0; j < 4; j++) {
            int n = nbase + j * 16 + cn;
            if (n >= N) continue;
            float bvv = bias ? bias[n] : 0.f;
#pragma unroll
            for (int i = 0; i < 8; i++) {
#pragma unroll
                for (int r = 0; r < 4; r++) {
                    float c = alpha * acc[i][j][r] + bvv;
                    if (act) c = fmaxf(c, 0.f);
                    cs1v[j] += c;
                    cs2v[j] += c * c;
                }
            }
        }
        bar_raw();
        float* red = (float*)smem;  // 2 x 2048 floats = 16 KB
        int pid = wm * 4 + kq;
#pragma unroll
        for (int j = 0; j < 4; j++) {
            int slot = wn * 64 + j * 16 + cn;
            red[pid * 256 + slot] = cs1v[j];
            red[2048 + pid * 256 + slot] = cs2v[j];
        }
        bar_raw();
        if (wm == 0 && kq == 0) {
#pragma unroll
            for (int j = 0; j < 4; j++) {
                int slot = wn * 64 + j * 16 + cn;
                float s = 0.f, s2 = 0.f;
#pragma unroll
                for (int p = 0; p < 8; p++) {
                    s += red[p * 256 + slot];
                    s2 += red[2048 + p * 256 + slot];
                }
                int n = col0 + slot;
                if (n < N) {
                    psOut[(size_t)by * N + n] = s;
                    ps2Out[(size_t)by * N + n] = s2;
                }
            }
        }
    }
}

// ---------------- BatchNorm finalize (partials fp32, from GEMM epilogue) ----------------
__global__ void bn_finalize_k(const float* __restrict__ ps, const float* __restrict__ ps2,
                              const float* __restrict__ g, const float* __restrict__ b,
                              float* __restrict__ scale, float* __restrict__ shift,
                              int Ncol, int nParts, int M) {
    int c = blockIdx.x * 256 + threadIdx.x;
    if (c >= Ncol) return;
    double s = 0, s2 = 0;
    for (int p = 0; p < nParts; p++) {
        s += ps[(size_t)p * Ncol + c];
        s2 += ps2[(size_t)p * Ncol + c];
    }
    double m = s / M;
    double v = s2 / M - m * m;
    float sc = g[c] / sqrtf((float)v + EPSV);
    scale[c] = sc;
    shift[c] = b[c] - (float)m * sc;
}

// BN apply + leaky -> bf16 [M][Cpad] (+ optional fp32 out [M][Nreal])
__global__ void bn_apply_k(const float* __restrict__ X, const float* __restrict__ scale,
                           const float* __restrict__ shift, __hip_bfloat16* __restrict__ Yb,
                           float* __restrict__ Yf, int Nreal, int Cpad) {
    int c = blockIdx.x * 256 + threadIdx.x;
    int r = blockIdx.y;
    if (c >= Cpad) return;
    float v = 0.f;
    if (c < Nreal) {
        v = fmaf(X[(size_t)r * Nreal + c], scale[c], shift[c]);
        v = v >= 0.f ? v : SLOPEV * v;
        if (Yf) Yf[(size_t)r * Nreal + c] = v;
    }
    Yb[(size_t)r * Cpad + c] = __float2bfloat16(v);
}

// ---------------- reductions ----------------
__device__ __forceinline__ double wave_sum_d(double v) {
#pragma unroll
    for (int o = 32; o > 0; o >>= 1) v += __shfl_down(v, o, 64);
    return v;
}
__device__ __forceinline__ float wave_sum_f(float v) {
#pragma unroll
    for (int o = 32; o > 0; o >>= 1) v += __shfl_down(v, o, 64);
    return v;
}
__device__ __forceinline__ float wave_max_f(float v) {
#pragma unroll
    for (int o = 32; o > 0; o >>= 1) v = fmaxf(v, __shfl_down(v, o, 64));
    return v;
}

// LayerNorm + leaky: fp32 [4096][2500] -> bf16 into A4cat cols [0,2500), pad [5000,KP4)
__global__ __launch_bounds__(256) void ln_leaky_k(const float* __restrict__ X,
                                                  const float* __restrict__ g,
                                                  const float* __restrict__ b,
                                                  __hip_bfloat16* __restrict__ A4) {
    int row = blockIdx.x;
    const float* xr = X + (size_t)row * DH;
    double s = 0, s2 = 0;
    for (int c = threadIdx.x; c < DH; c += 256) {
        float x = xr[c];
        s += x;
        s2 += (double)x * x;
    }
    __shared__ double sb[4], sb2[4];
    int lane = threadIdx.x & 63, w = threadIdx.x >> 6;
    s = wave_sum_d(s);
    s2 = wave_sum_d(s2);
    if (lane == 0) { sb[w] = s; sb2[w] = s2; }
    __syncthreads();
    double S = sb[0] + sb[1] + sb[2] + sb[3];
    double S2 = sb2[0] + sb2[1] + sb2[2] + sb2[3];
    double m = S / DH;
    double v = S2 / DH - m * m;
    float inv = 1.f / sqrtf((float)v + EPSV);
    float mf = (float)m;
    __hip_bfloat16* yr = A4 + (size_t)row * KP4;
    for (int c = threadIdx.x; c < DH; c += 256) {
        float x = (xr[c] - mf) * inv * g[c] + b[c];
        x = x >= 0.f ? x : SLOPEV * x;
        yr[c] = __float2bfloat16(x);
    }
    if (threadIdx.x < KP4 - KC4) yr[KC4 + threadIdx.x] = __float2bfloat16(0.f);
}

// single-pass softmax over 4096-wide rows: row in registers (16 f/thread)
__global__ __launch_bounds__(256) void softmax1_k(const float* __restrict__ X,
                                                  __hip_bfloat16* __restrict__ Y) {
    int row = blockIdx.x, t = threadIdx.x;
    const f32x4* xr = reinterpret_cast<const f32x4*>(X + (size_t)row * NTRAIN);
    f32x4 v[4];
    float mx = -3.4e38f;
#pragma unroll
    for (int i = 0; i < 4; i++) {
        v[i] = xr[i * 256 + t];
#pragma unroll
        for (int c = 0; c < 4; c++) mx = fmaxf(mx, v[i][c]);
    }
    __shared__ float sb[4];
    int lane = t & 63, w = t >> 6;
    mx = wave_max_f(mx);
    if (lane == 0) sb[w] = mx;
    __syncthreads();
    mx = fmaxf(fmaxf(sb[0], sb[1]), fmaxf(sb[2], sb[3]));
    float s = 0.f;
#pragma unroll
    for (int i = 0; i < 4; i++)
#pragma unroll
        for (int c = 0; c < 4; c++) {
            float e = expf(v[i][c] - mx);
            v[i][c] = e;
            s += e;
        }
    s = wave_sum_f(s);
    __syncthreads();  // sb reuse
    if (lane == 0) sb[w] = s;
    __syncthreads();
    float inv = 1.f / (sb[0] + sb[1] + sb[2] + sb[3]);
    ushort4* yr = reinterpret_cast<ushort4*>(Y + (size_t)row * NTRAIN);
#pragma unroll
    for (int i = 0; i < 4; i++) {
        ushort4 o;
        o.x = bfbits(v[i][0] * inv);
        o.y = bfbits(v[i][1] * inv);
        o.z = bfbits(v[i][2] * inv);
        o.w = bfbits(v[i][3] * inv);
        yr[i * 256 + t] = o;
    }
}

// final tiny GEMM: Y[4096][16] = X[4096][2500] @ Wce[2500][16] + bce
__global__ __launch_bounds__(256) void head_k(const float* __restrict__ X,
                                              const float* __restrict__ Wce,
                                              const float* __restrict__ bce,
                                              float* __restrict__ Y) {
    int row = blockIdx.x;
    int n = threadIdx.x & 15, part = threadIdx.x >> 4;
    const float* xr = X + (size_t)row * DH;
    float s = 0.f;
    for (int k = part; k < DH; k += 16) s += xr[k] * Wce[k * 16 + n];
    __shared__ float red[256];
    red[threadIdx.x] = s;
    __syncthreads();
    for (int off = 8; off >= 1; off >>= 1) {
        if (part < off) red[threadIdx.x] += red[threadIdx.x + off * 16];
        __syncthreads();
    }
    if (part == 0) Y[row * 16 + n] = red[n] + bce[n];
}

// ---------------- launch ----------------
extern "C" void kernel_launch(void* const* d_in, const int* in_sizes, int n_in,
                              void* d_out, int out_size, void* d_ws, size_t ws_size,
                              hipStream_t stream) {
    const float* gene    = (const float*)d_in[0];
    const float* trainf  = (const float*)d_in[1];
    const float* yhat    = (const float*)d_in[2];
    const int*   esrc    = (const int*)d_in[3];
    const int*   edst    = (const int*)d_in[4];
    const float* W_self3 = (const float*)d_in[5];
    const float* W_neigh3= (const float*)d_in[6];
    const float* b3      = (const float*)d_in[7];
    const float* bn3_g   = (const float*)d_in[8];
    const float* bn3_b   = (const float*)d_in[9];
    const float* Wq      = (const float*)d_in[10];
    const float* Wk      = (const float*)d_in[11];
    const float* Wv      = (const float*)d_in[12];
    const float* bq      = (const float*)d_in[13];
    const float* bk      = (const float*)d_in[14];
    const float* bv      = (const float*)d_in[15];
    const float* Wo      = (const float*)d_in[16];
    const float* bo      = (const float*)d_in[17];
    const float* ln2_g   = (const float*)d_in[18];
    const float* ln2_b   = (const float*)d_in[19];
    const float* W_self4 = (const float*)d_in[20];
    const float* W_neigh4= (const float*)d_in[21];
    const float* b4      = (const float*)d_in[22];
    const float* bn4_g   = (const float*)d_in[23];
    const float* bn4_b   = (const float*)d_in[24];
    const float* W_lin2  = (const float*)d_in[25];
    const float* b_lin2  = (const float*)d_in[26];
    const float* W_ce    = (const float*)d_in[27];
    const float* b_ce    = (const float*)d_in[28];

    char* ws = (char*)d_ws;
    size_t off = 0;
    auto alloc = [&](size_t bytes) -> void* {
        void* p = ws + off;
        off = (off + bytes + 255) & ~(size_t)255;
        return p;
    };
    __hip_bfloat16* A3cat  = (__hip_bfloat16*)alloc((size_t)NTRAIN * KP3 * 2);   // also attn_bf
    __hip_bfloat16* A4cat  = (__hip_bfloat16*)alloc((size_t)NTRAIN * KP4 * 2);
    __hip_bfloat16* h_bf   = (__hip_bfloat16*)alloc((size_t)NTRAIN * KPH * 2);   // also xhat_bf
    __hip_bfloat16* qkv_bf = (__hip_bfloat16*)alloc((size_t)NTRAIN * NQKV * 2);  // also ao_bf
    __hip_bfloat16* W3t    = (__hip_bfloat16*)alloc((size_t)NPW * KP3 * 2);      // also W4t
    __hip_bfloat16* Wqkvt  = (__hip_bfloat16*)alloc((size_t)3 * NPW * KPH * 2);  // also Wot/Wlin2t
    float*  bigC   = (float*)alloc((size_t)NTRAIN * NTRAIN * 4);                 // also vT_bf
    float*  ps     = (float*)alloc((size_t)16 * DH * 4);
    float*  ps2    = (float*)alloc((size_t)16 * DH * 4);
    float*  scale  = (float*)alloc(DH * 4);
    float*  shift  = (float*)alloc(DH * 4);
    float*  bqkv   = (float*)alloc(NQKV * 4);
    int*    deg    = (int*)alloc(NTRAIN * 4);
    int*    indptr = (int*)alloc((NTRAIN + 1) * 4);
    int*    cursor = (int*)alloc(NTRAIN * 4);
    int*    csr_src= (int*)alloc(NEDGES * 4);
    __hip_bfloat16* attn_bf = A3cat;   // [4096][4096] (A3cat dead after conv3)
    __hip_bfloat16* W4t     = W3t;     // after conv3 gemm
    __hip_bfloat16* Wot     = Wqkvt;   // after qkv gemm
    __hip_bfloat16* Wlin2t  = Wqkvt;   // after Wo gemm
    __hip_bfloat16* xhat_bf = h_bf;    // h_bf dead after qkv gemm
    __hip_bfloat16* ao_bf   = qkv_bf;  // q/k/v dead after scores+vT
    __hip_bfloat16* vT_bf   = (__hip_bfloat16*)bigC;  // built after softmax, dead before Wo gemm
    // gene_bf (100.2 MB) aliases W3t+Wqkvt+bigC span (133 MB): dead before wtrans W3t
    short* gene_bf = (short*)W3t;

    float* xhat = (float*)d_out;                       // [4096][2500]
    float* yout = (float*)d_out + (size_t)NTRAIN * DH; // [4096][16]

    auto gemm = [&](const void* A, const void* Bt, const float* bias, float* Cf,
                    __hip_bfloat16* Cb, float* psO, float* ps2O, int NpadCols, int Nreal,
                    int K, int sA, int sB, int ldc, int nmod, float alpha, int act) {
        dim3 g(NpadCols / 256, NTRAIN / 256);
        gemm256_k<<<g, 512, 0, stream>>>((const short*)A, (const short*)Bt, bias, Cf, Cb,
                                         psO, ps2O, Nreal, K, sA, sB, ldc, nmod, alpha, act);
    };

    // ---- CSR + bf16 gene + neighbor mean ----
    hipMemsetAsync(deg, 0, NTRAIN * 4, stream);
    count_deg_k<<<NEDGES / 256, 256, 0, stream>>>(edst, deg);
    scan_deg_k<<<1, 1024, 0, stream>>>(deg, indptr, cursor);
    scatter_edges_k<<<NEDGES / 256, 256, 0, stream>>>(esrc, edst, cursor, csr_src);
    gene2bf_k<<<dim3(2, 20000), 256, 0, stream>>>(gene, gene_bf);
    sage_mean_k<<<NTRAIN, 256, 0, stream>>>(gene_bf, indptr, csr_src, A3cat, A4cat);
    dst_build_k<<<dim3((KP3 + 255) / 256, NTRAIN), 256, 0, stream>>>(trainf, yhat, A3cat);
    // W3t = [W_self3; W_neigh3]^T -> [2560][5184] (overwrites gene_bf region: sage done)
    wtrans_k<<<dim3(KP3 / 32, NPW / 32), 256, 0, stream>>>(W_self3, W_neigh3, DH, W3t, DH, 2675, KC3, KP3, NPW);

    // ---- conv3 (K=5184 GEMM, BN partials fused) ----
    gemm(A3cat, W3t, b3, bigC, nullptr, ps, ps2, NPW, DH, KP3, KP3, KP3, DH, DH, 1.f, 0);
    bn_finalize_k<<<(DH + 255) / 256, 256, 0, stream>>>(ps, ps2, bn3_g, bn3_b, scale, shift, DH, 16, NTRAIN);
    bn_apply_k<<<dim3((KPH + 255) / 256, NTRAIN), 256, 0, stream>>>(bigC, scale, shift, h_bf, nullptr, DH, KPH);

    // ---- attention ----
    // Wqkvt = [Wq^T | Wk^T | Wv^T] — single 3-slab dispatch (full-fill per slab)
    wtrans3_k<<<dim3(KPH / 32, NPW / 32, 3), 256, 0, stream>>>(Wq, Wk, Wv, Wqkvt);
    qkv_bias_k<<<NQKV / 256, 256, 0, stream>>>(bq, bk, bv, bqkv);
    // fused qkv: [4096][7680] bf16, grid 30x16=480 blocks
    gemm(h_bf, Wqkvt, bqkv, nullptr, qkv_bf, nullptr, nullptr, NQKV, DH, KPH, KPH, KPH, NQKV, KPH, 1.f, 0);
    // scores = q @ k^T * (1/50) -> bigC [4096][4096]
    gemm(qkv_bf, qkv_bf + KPH, nullptr, bigC, nullptr, nullptr, nullptr, NTRAIN, NTRAIN, KPH, NQKV, NQKV, NTRAIN, NTRAIN, 0.02f, 0);
    softmax1_k<<<NTRAIN, 256, 0, stream>>>(bigC, attn_bf);
    // vT = v^T -> bf16 [2560][4096] (into bigC alias; scores dead after softmax)
    btrans_k<<<dim3(NTRAIN / 32, KPH / 32), 256, 0, stream>>>(qkv_bf + 2 * KPH, NQKV, vT_bf);
    // attn @ v -> direct bf16 ao_bf (overwrites qkv region; q/k/v dead)
    gemm(attn_bf, vT_bf, nullptr, nullptr, ao_bf, nullptr, nullptr, NPW, DH, NTRAIN, NTRAIN, NTRAIN, KPH, KPH, 1.f, 0);
    // @ Wo + bo -> bigC (vT dead), then LN -> A4cat
    wtrans_k<<<dim3(KPH / 32, NPW / 32), 256, 0, stream>>>(Wo, nullptr, DH, Wot, DH, DH, DH, KPH, NPW);
    gemm(ao_bf, Wot, bo, bigC, nullptr, nullptr, nullptr, NPW, DH, KPH, KPH, KPH, DH, DH, 1.f, 0);
    ln_leaky_k<<<NTRAIN, 256, 0, stream>>>(bigC, ln2_g, ln2_b, A4cat);

    // ---- conv4 (K=5056 GEMM, BN partials fused) ----
    wtrans_k<<<dim3(KP4 / 32, NPW / 32), 256, 0, stream>>>(W_self4, W_neigh4, DH, W4t, DH, DH, KC4, KP4, NPW);
    gemm(A4cat, W4t, b4, bigC, nullptr, ps, ps2, NPW, DH, KP4, KP4, KP4, DH, DH, 1.f, 0);
    bn_finalize_k<<<(DH + 255) / 256, 256, 0, stream>>>(ps, ps2, bn4_g, bn4_b, scale, shift, DH, 16, NTRAIN);
    bn_apply_k<<<dim3((KPH + 255) / 256, NTRAIN), 256, 0, stream>>>(bigC, scale, shift, xhat_bf, xhat, DH, KPH);

    // ---- head ----
    wtrans_k<<<dim3(KPH / 32, NPW / 32), 256, 0, stream>>>(W_lin2, nullptr, DH, Wlin2t, DH, DH, DH, KPH, NPW);
    gemm(xhat_bf, Wlin2t, b_lin2, bigC, nullptr, nullptr, nullptr, NPW, DH, KPH, KPH, KPH, DH, DH, 1.f, 1);  // relu
    head_k<<<NTRAIN, 256, 0, stream>>>(bigC, W_ce, b_ce, yout);
    (void)ws_size; (void)n_in; (void)in_sizes; (void)out_size;
}